// Round 6
// baseline (191.676 us; speedup 1.0000x reference)
//
#include <hip/hip_runtime.h>

// Edge (replicate) pad, width 2 on H and W.
// In:  (32, 256, 56, 56) fp32  -> NC = 8192 planes of 56x56
// Out: (32, 256, 60, 60) fp32
//
// v5 = round-0 structure (best measured, simplest) with ONE change:
// normal cached stores instead of __builtin_nontemporal_store.
// Single-variable test of store cache policy: NT bypasses L2 and may cap
// per-CU write throughput; the 6.85 TB/s rocclr fills on this machine use
// cached writes. Everything else identical to the 187.8 µs baseline.
//
// One thread per output float4 (row = 60 floats = 15 float4).
// Wave-uniform memory: ALL lanes do one dwordx4 at a clamped window base,
// edge cases (w4=0 / w4=14) are fixed up with register permutes only —
// no loads under divergent control flow (1 load + 1 store per thread).
//   w4=0 : base=0,  window {s0..s3},   out {s0,s0,s0,s1}   = (x,x,x,y)
//   w4=14: base=52, window {s52..s55}, out {s54,s55,s55,s55} = (z,w,w,w)
//   else : base=ow0-2, identity

#define IN_H  56
#define IN_W  56
#define OUT_H 60
#define OUT_W 60
#define PAD   2
#define W4    (OUT_W / 4)   // 15 float4 per output row

typedef float f4u __attribute__((ext_vector_type(4), aligned(4)));
typedef float f4a __attribute__((ext_vector_type(4), aligned(16)));

__global__ __launch_bounds__(256) void pad2d_edge_kernel(
    const float* __restrict__ in, float* __restrict__ out, int n_vec) {
    int idx = blockIdx.x * blockDim.x + threadIdx.x;
    if (idx >= n_vec) return;

    int w4 = idx % W4;
    int t  = idx / W4;
    int oh = t % OUT_H;
    int nc = t / OUT_H;

    int ih = min(max(oh - PAD, 0), IN_H - 1);
    const float* src = in + (size_t)nc * (IN_H * IN_W) + (size_t)ih * IN_W;

    int ow0  = w4 * 4;
    int base = min(max(ow0 - PAD, 0), IN_W - 4);   // 0..52, always in-bounds
    f4u u = *reinterpret_cast<const f4u*>(src + base);

    // Register-only edge fixup (compiles to cndmasks, no divergent memory).
    f4a v;
    v.x = (w4 == W4 - 1) ? u.z : u.x;
    v.y = (w4 == 0)      ? u.x : ((w4 == W4 - 1) ? u.w : u.y);
    v.z = (w4 == 0)      ? u.x : ((w4 == W4 - 1) ? u.w : u.z);
    v.w = (w4 == 0)      ? u.y : ((w4 == W4 - 1) ? u.w : u.w);

    // Cached (non-NT) store — the one change vs the 187.8 µs baseline.
    reinterpret_cast<f4a*>(out)[idx] = v;
}

extern "C" void kernel_launch(void* const* d_in, const int* in_sizes, int n_in,
                              void* d_out, int out_size, void* d_ws, size_t ws_size,
                              hipStream_t stream) {
    const float* x = (const float*)d_in[0];
    float* out = (float*)d_out;

    int n_vec = out_size / 4;  // 32*256*60*60/4 = 7,372,800 threads
    int block = 256;
    int grid = (n_vec + block - 1) / block;
    pad2d_edge_kernel<<<grid, block, 0, stream>>>(x, out, n_vec);
}